// Round 2
// baseline (320.824 us; speedup 1.0000x reference)
//
#include <hip/hip_runtime.h>
#include <hip/hip_bf16.h>

// X: [16, 2048, 128] f32, Y: [16, 2048, 128] f32 -> out: [16, 2048, 2048] f32
// out[b,n,m] = 1/(1+sqrt(max(||x||^2+||y||^2-2 x.y, 1e-7)))
#define Bb   16
#define Nn   2048
#define Mm   2048
#define Dd   128
#define TILE 128
#define NWG  (Bb * (Nn / TILE) * (Mm / TILE))   // 4096

typedef __attribute__((ext_vector_type(4))) float          f32x4;
typedef __attribute__((ext_vector_type(8))) unsigned short u16x8;
typedef __attribute__((ext_vector_type(8))) __bf16         bf16x8;

__device__ __forceinline__ unsigned short f32_to_bf16_rne(float f) {
  unsigned int u = __builtin_bit_cast(unsigned int, f);
  u += 0x7fffu + ((u >> 16) & 1u);   // round-to-nearest-even
  return (unsigned short)(u >> 16);
}

// One block = one 128x128 output tile. 4 waves, each a 64x64 quadrant.
// Y tile staged to LDS (bf16, swizzled); X fragments loaded global->reg per
// k-step (each wave-load covers 16 full 128B lines). LDS = 34KB -> 4 blocks/CU.
__global__ __launch_bounds__(256, 4)
void dist_sim_kernel(const float* __restrict__ X, const float* __restrict__ Y,
                     float* __restrict__ out) {
  __shared__ alignas(16) unsigned short Ys[TILE * Dd];  // 32 KB
  __shared__ float ysq[TILE];
  __shared__ float xsq[TILE];

  const int tid = threadIdx.x;

  // Bijective XCD-chunked swizzle (NWG % 8 == 0): each XCD owns 512
  // consecutive logical tiles -> X-tile reuse (over bm) and Y-tile reuse
  // (over bn) stay in one XCD's L2.
  const int wg  = blockIdx.x;
  const int swz = (wg & 7) * (NWG / 8) + (wg >> 3);
  const int bm  = swz & 15;          // M-tile (fastest)
  const int bn  = (swz >> 4) & 15;   // N-tile
  const int b   = swz >> 8;          // batch

  const float* Xb = X + ((size_t)b * Nn + (size_t)bn * TILE) * Dd;
  const float* Yb = Y + ((size_t)b * Mm + (size_t)bm * TILE) * Dd;

  // ---------------- stage Y: global f32 -> LDS bf16 + f32 norms -------------
  const int sub = tid >> 4;
  const int c0  = (tid & 15) * 8;
  #pragma unroll
  for (int it = 0; it < 8; ++it) {
    const int row = it * 16 + sub;
    const float* p = Yb + row * Dd + c0;
    f32x4 v0 = *(const f32x4*)(p);
    f32x4 v1 = *(const f32x4*)(p + 4);
    u16x8 w;
    float ss = 0.f;
    #pragma unroll
    for (int e = 0; e < 4; ++e) {
      ss += v0[e] * v0[e] + v1[e] * v1[e];
      w[e]     = f32_to_bf16_rne(v0[e]);
      w[e + 4] = f32_to_bf16_rne(v1[e]);
    }
    ss += __shfl_xor(ss, 1);
    ss += __shfl_xor(ss, 2);
    ss += __shfl_xor(ss, 4);
    ss += __shfl_xor(ss, 8);
    const int idx = (row * Dd + c0) ^ ((row & 7) << 3);  // bank swizzle (shorts)
    *(u16x8*)&Ys[idx] = w;
    if ((tid & 15) == 0) ysq[row] = ss;
  }

  const int lane = tid & 63;
  const int wid  = tid >> 6;           // 0..3
  const int wr   = (wid >> 1) * 64;    // wave row offset
  const int wc   = (wid & 1) * 64;     // wave col offset
  const int fr   = lane & 15;
  const int kg   = lane >> 4;          // 0..3

  // Per-wave X base: lane (kg,fr) reads row wr+i*16+fr, 8 floats at kg*8+kk*32.
  const float* xbase = Xb + (size_t)(wr + fr) * Dd + kg * 8;

  f32x4 acc[4][4];
  #pragma unroll
  for (int i = 0; i < 4; ++i)
    #pragma unroll
    for (int j = 0; j < 4; ++j)
      acc[i][j] = (f32x4){0.f, 0.f, 0.f, 0.f};
  float ss4[4] = {0.f, 0.f, 0.f, 0.f};

  __syncthreads();

  // ---------------- main loop: K = 4 x 32 -----------------------------------
  #pragma unroll
  for (int kk = 0; kk < 4; ++kk) {
    bf16x8 a[4];
    #pragma unroll
    for (int i = 0; i < 4; ++i) {
      const float* p = xbase + i * 16 * Dd + kk * 32;
      f32x4 v0 = *(const f32x4*)(p);
      f32x4 v1 = *(const f32x4*)(p + 4);
      u16x8 w;
      float ss = 0.f;
      #pragma unroll
      for (int e = 0; e < 4; ++e) {
        ss += v0[e] * v0[e] + v1[e] * v1[e];
        w[e]     = f32_to_bf16_rne(v0[e]);
        w[e + 4] = f32_to_bf16_rne(v1[e]);
      }
      ss4[i] += ss;
      a[i] = __builtin_bit_cast(bf16x8, w);
    }
    bf16x8 bfj[4];
    #pragma unroll
    for (int j = 0; j < 4; ++j) {
      const int row = wc + j * 16 + fr;
      const int idx = (row * Dd + kk * 32 + kg * 8) ^ ((row & 7) << 3);
      bfj[j] = __builtin_bit_cast(bf16x8, *(const u16x8*)&Ys[idx]);
    }
    #pragma unroll
    for (int i = 0; i < 4; ++i)
      #pragma unroll
      for (int j = 0; j < 4; ++j)
        acc[i][j] = __builtin_amdgcn_mfma_f32_16x16x32_bf16(a[i], bfj[j], acc[i][j], 0, 0, 0);
  }

  // X row norms: each lane holds the sum of its (kg) k-slices; fold kg groups.
  #pragma unroll
  for (int i = 0; i < 4; ++i) {
    float s = ss4[i];
    s += __shfl_xor(s, 16);
    s += __shfl_xor(s, 32);
    if (lane < 16) xsq[wr + i * 16 + lane] = s;  // wave-local rows: no barrier
  }

  // ---------------- epilogue: d2 -> 1/(1+sqrt(d2)) --------------------------
  // C/D layout: col = lane&15, row = (lane>>4)*4 + reg.
  float yv[4];
  #pragma unroll
  for (int j = 0; j < 4; ++j) yv[j] = ysq[wc + j * 16 + fr];

  float* outb = out + (size_t)b * Nn * Mm;
  #pragma unroll
  for (int i = 0; i < 4; ++i) {
    float xv[4];
    #pragma unroll
    for (int r = 0; r < 4; ++r) xv[r] = xsq[wr + i * 16 + kg * 4 + r];
    #pragma unroll
    for (int j = 0; j < 4; ++j) {
      const int gcol = bm * TILE + wc + j * 16 + fr;
      #pragma unroll
      for (int r = 0; r < 4; ++r) {
        const int row_l = wr + i * 16 + kg * 4 + r;
        float d2 = fmaf(-2.0f, acc[i][j][r], xv[r] + yv[j]);
        d2 = fmaxf(d2, 1e-7f);
        const float s = __builtin_amdgcn_sqrtf(d2);   // 1-ulp HW sqrt
        const float o = __builtin_amdgcn_rcpf(1.0f + s);  // 1-ulp HW rcp
        outb[(size_t)(bn * TILE + row_l) * Mm + gcol] = o;
      }
    }
  }
}

extern "C" void kernel_launch(void* const* d_in, const int* in_sizes, int n_in,
                              void* d_out, int out_size, void* d_ws, size_t ws_size,
                              hipStream_t stream) {
  const float* X = (const float*)d_in[0];
  const float* Y = (const float*)d_in[1];
  float* out = (float*)d_out;
  dist_sim_kernel<<<dim3(NWG), dim3(256, 1, 1), 0, stream>>>(X, Y, out);
}

// Round 3
// 255.985 us; speedup vs baseline: 1.2533x; 1.2533x over previous
//
#include <hip/hip_runtime.h>
#include <hip/hip_bf16.h>

// X: [16, 2048, 128] f32, Y: [16, 2048, 128] f32 -> out: [16, 2048, 2048] f32
// out[b,n,m] = 1/(1+sqrt(max(||x||^2+||y||^2-2 x.y, 1e-7)))
#define Bb   16
#define Nn   2048
#define Mm   2048
#define Dd   128
#define TILE 128
#define KH   64                                  // K half staged per pass
#define NWG  (Bb * (Nn / TILE) * (Mm / TILE))    // 4096

typedef __attribute__((ext_vector_type(4))) float          f32x4;
typedef __attribute__((ext_vector_type(8))) unsigned short u16x8;
typedef __attribute__((ext_vector_type(8))) __bf16         bf16x8;

__device__ __forceinline__ unsigned short f32_to_bf16_rne(float f) {
  unsigned int u = __builtin_bit_cast(unsigned int, f);
  u += 0x7fffu + ((u >> 16) & 1u);
  return (unsigned short)(u >> 16);
}

// One block = one 128x128 output tile, 4 waves = 64x64 quadrants.
// Both tiles LDS-staged (bf16, swizzled) in K-halves of 64: LDS = 33 KB
// -> 4 blocks/CU, and NO operand traffic competes with the output stream in L2.
__global__ __launch_bounds__(256, 4)
void dist_sim_kernel(const float* __restrict__ X, const float* __restrict__ Y,
                     float* __restrict__ out) {
  __shared__ alignas(16) unsigned short Xs[TILE * KH];  // 16 KB
  __shared__ alignas(16) unsigned short Ys[TILE * KH];  // 16 KB
  __shared__ float xsq[TILE];
  __shared__ float ysq[TILE];

  const int tid = threadIdx.x;

  // Bijective XCD-chunked swizzle (NWG % 8 == 0).
  const int wg  = blockIdx.x;
  const int swz = (wg & 7) * (NWG / 8) + (wg >> 3);
  const int bm  = swz & 15;
  const int bn  = (swz >> 4) & 15;
  const int b   = swz >> 8;

  const float* Xb = X + ((size_t)b * Nn + (size_t)bn * TILE) * Dd;
  const float* Yb = Y + ((size_t)b * Mm + (size_t)bm * TILE) * Dd;

  // Staging map: thread t -> row rsub+32*it, 8 floats at col c0 within the half.
  const int rsub = tid >> 3;        // 0..31
  const int c0   = (tid & 7) * 8;   // 0..56

  float ssx[4] = {0.f, 0.f, 0.f, 0.f};
  float ssy[4] = {0.f, 0.f, 0.f, 0.f};

  const int lane = tid & 63;
  const int wid  = tid >> 6;
  const int wr   = (wid >> 1) * 64;
  const int wc   = (wid & 1) * 64;
  const int fr   = lane & 15;
  const int kg   = lane >> 4;

  f32x4 acc[4][4];
  #pragma unroll
  for (int i = 0; i < 4; ++i)
    #pragma unroll
    for (int j = 0; j < 4; ++j)
      acc[i][j] = (f32x4){0.f, 0.f, 0.f, 0.f};

  #pragma unroll
  for (int half = 0; half < 2; ++half) {
    if (half == 1) __syncthreads();  // protect LDS re-stage from half-0 readers

    // ---- stage: global f32 -> LDS bf16 (swizzled), accumulate f32 norms ----
    #pragma unroll
    for (int it = 0; it < 4; ++it) {
      const int row = it * 32 + rsub;
      {
        const float* p = Xb + row * Dd + half * KH + c0;
        f32x4 v0 = *(const f32x4*)(p);
        f32x4 v1 = *(const f32x4*)(p + 4);
        u16x8 w;
        float s = 0.f;
        #pragma unroll
        for (int e = 0; e < 4; ++e) {
          s += v0[e] * v0[e] + v1[e] * v1[e];
          w[e]     = f32_to_bf16_rne(v0[e]);
          w[e + 4] = f32_to_bf16_rne(v1[e]);
        }
        ssx[it] += s;
        const int idx = (row * KH + c0) ^ ((row & 7) << 3);  // bank swizzle
        *(u16x8*)&Xs[idx] = w;
      }
      {
        const float* p = Yb + row * Dd + half * KH + c0;
        f32x4 v0 = *(const f32x4*)(p);
        f32x4 v1 = *(const f32x4*)(p + 4);
        u16x8 w;
        float s = 0.f;
        #pragma unroll
        for (int e = 0; e < 4; ++e) {
          s += v0[e] * v0[e] + v1[e] * v1[e];
          w[e]     = f32_to_bf16_rne(v0[e]);
          w[e + 4] = f32_to_bf16_rne(v1[e]);
        }
        ssy[it] += s;
        const int idx = (row * KH + c0) ^ ((row & 7) << 3);
        *(u16x8*)&Ys[idx] = w;
      }
    }

    // After the second stage pass, fold and publish the f32 row norms
    // (8 lanes per row; lanes sharing a row are consecutive within the wave).
    if (half == 1) {
      #pragma unroll
      for (int it = 0; it < 4; ++it) {
        float sx = ssx[it], sy = ssy[it];
        sx += __shfl_xor(sx, 1); sy += __shfl_xor(sy, 1);
        sx += __shfl_xor(sx, 2); sy += __shfl_xor(sy, 2);
        sx += __shfl_xor(sx, 4); sy += __shfl_xor(sy, 4);
        if ((tid & 7) == 0) {
          xsq[it * 32 + rsub] = sx;
          ysq[it * 32 + rsub] = sy;
        }
      }
    }
    __syncthreads();

    // ---- MFMA over this K-half (2 x K=32 steps) ----------------------------
    #pragma unroll
    for (int kk = 0; kk < 2; ++kk) {
      bf16x8 a[4], bfj[4];
      #pragma unroll
      for (int i = 0; i < 4; ++i) {
        const int row = wr + i * 16 + fr;
        const int idx = (row * KH + kk * 32 + kg * 8) ^ ((row & 7) << 3);
        a[i] = __builtin_bit_cast(bf16x8, *(const u16x8*)&Xs[idx]);
      }
      #pragma unroll
      for (int j = 0; j < 4; ++j) {
        const int row = wc + j * 16 + fr;
        const int idx = (row * KH + kk * 32 + kg * 8) ^ ((row & 7) << 3);
        bfj[j] = __builtin_bit_cast(bf16x8, *(const u16x8*)&Ys[idx]);
      }
      #pragma unroll
      for (int i = 0; i < 4; ++i)
        #pragma unroll
        for (int j = 0; j < 4; ++j)
          acc[i][j] = __builtin_amdgcn_mfma_f32_16x16x32_bf16(a[i], bfj[j], acc[i][j], 0, 0, 0);
    }
  }

  // ---- epilogue: d2 -> 1/(1+sqrt(d2)) --------------------------------------
  // C/D layout: col = lane&15 (fr), row = kg*4 + reg.
  // Loop order (i, r) outer, j inner: the 4 stores for one output row cover
  // contiguous 256 B back-to-back -> L2 merges full 128 B lines.
  float yv[4];
  #pragma unroll
  for (int j = 0; j < 4; ++j) yv[j] = ysq[wc + j * 16 + fr];

  float* outb = out + (size_t)b * Nn * Mm + (size_t)bm * TILE + wc;
  #pragma unroll
  for (int i = 0; i < 4; ++i) {
    #pragma unroll
    for (int r = 0; r < 4; ++r) {
      const int row_l = wr + i * 16 + kg * 4 + r;
      const float xv  = xsq[row_l];
      float* orow = outb + (size_t)(bn * TILE + row_l) * Mm;
      #pragma unroll
      for (int j = 0; j < 4; ++j) {
        float d2 = fmaf(-2.0f, acc[i][j][r], xv + yv[j]);
        d2 = fmaxf(d2, 1e-7f);
        const float s = __builtin_amdgcn_sqrtf(d2);
        orow[j * 16 + fr] = __builtin_amdgcn_rcpf(1.0f + s);
      }
    }
  }
}

extern "C" void kernel_launch(void* const* d_in, const int* in_sizes, int n_in,
                              void* d_out, int out_size, void* d_ws, size_t ws_size,
                              hipStream_t stream) {
  const float* X = (const float*)d_in[0];
  const float* Y = (const float*)d_in[1];
  float* out = (float*)d_out;
  dist_sim_kernel<<<dim3(NWG), dim3(256, 1, 1), 0, stream>>>(X, Y, out);
}

// Round 4
// 199.551 us; speedup vs baseline: 1.6077x; 1.2828x over previous
//
#include <hip/hip_runtime.h>
#include <hip/hip_bf16.h>

// X: [16, 2048, 128] f32, Y: [16, 2048, 128] f32 -> out: [16, 2048, 2048] f32
// out[b,n,m] = 1/(1+sqrt(max(||x||^2+||y||^2-2 x.y, 1e-7)))
#define Bb   16
#define Nn   2048
#define Mm   2048
#define Dd   128
#define TILE 128
#define KH   64                                  // K half staged per pass
#define NWG  (Bb * (Nn / TILE) * (Mm / TILE))    // 4096

typedef __attribute__((ext_vector_type(4))) float          f32x4;
typedef __attribute__((ext_vector_type(8))) unsigned short u16x8;
typedef __attribute__((ext_vector_type(8))) __bf16         bf16x8;

__device__ __forceinline__ unsigned short f32_to_bf16_rne(float f) {
  unsigned int u = __builtin_bit_cast(unsigned int, f);
  u += 0x7fffu + ((u >> 16) & 1u);
  return (unsigned short)(u >> 16);
}

// One block = one 128x128 output tile, 4 waves = 64x64 quadrants.
// Swapped-operand MFMA puts 4 consecutive output floats in each lane's regs;
// an LDS transpose (reusing the staging buffer) then lets every global store
// instruction cover full 128B lines -> each output line written exactly once.
__global__ __launch_bounds__(256, 4)
void dist_sim_kernel(const float* __restrict__ X, const float* __restrict__ Y,
                     float* __restrict__ out) {
  __shared__ alignas(16) unsigned short smem[2 * TILE * KH];  // 32 KB
  __shared__ float xsq[TILE];
  __shared__ float ysq[TILE];
  unsigned short* Xs = smem;
  unsigned short* Ys = smem + TILE * KH;

  const int tid = threadIdx.x;

  // Bijective XCD-chunked swizzle (NWG % 8 == 0).
  const int wg  = blockIdx.x;
  const int swz = (wg & 7) * (NWG / 8) + (wg >> 3);
  const int bm  = swz & 15;
  const int bn  = (swz >> 4) & 15;
  const int b   = swz >> 8;

  const float* Xb = X + ((size_t)b * Nn + (size_t)bn * TILE) * Dd;
  const float* Yb = Y + ((size_t)b * Mm + (size_t)bm * TILE) * Dd;

  const int rsub = tid >> 3;        // 0..31
  const int c0   = (tid & 7) * 8;   // 0..56

  float ssx[4] = {0.f, 0.f, 0.f, 0.f};
  float ssy[4] = {0.f, 0.f, 0.f, 0.f};

  const int lane = tid & 63;
  const int wid  = tid >> 6;
  const int wr   = (wid >> 1) * 64;
  const int wc   = (wid & 1) * 64;
  const int fr   = lane & 15;
  const int kg   = lane >> 4;

  f32x4 acc[4][4];
  #pragma unroll
  for (int i = 0; i < 4; ++i)
    #pragma unroll
    for (int j = 0; j < 4; ++j)
      acc[i][j] = (f32x4){0.f, 0.f, 0.f, 0.f};

  #pragma unroll
  for (int half = 0; half < 2; ++half) {
    if (half == 1) __syncthreads();

    // ---- stage: global f32 -> LDS bf16 (swizzled), accumulate f32 norms ----
    #pragma unroll
    for (int it = 0; it < 4; ++it) {
      const int row = it * 32 + rsub;
      {
        const float* p = Xb + row * Dd + half * KH + c0;
        f32x4 v0 = *(const f32x4*)(p);
        f32x4 v1 = *(const f32x4*)(p + 4);
        u16x8 w;
        float s = 0.f;
        #pragma unroll
        for (int e = 0; e < 4; ++e) {
          s += v0[e] * v0[e] + v1[e] * v1[e];
          w[e]     = f32_to_bf16_rne(v0[e]);
          w[e + 4] = f32_to_bf16_rne(v1[e]);
        }
        ssx[it] += s;
        const int idx = (row * KH + c0) ^ ((row & 7) << 3);
        *(u16x8*)&Xs[idx] = w;
      }
      {
        const float* p = Yb + row * Dd + half * KH + c0;
        f32x4 v0 = *(const f32x4*)(p);
        f32x4 v1 = *(const f32x4*)(p + 4);
        u16x8 w;
        float s = 0.f;
        #pragma unroll
        for (int e = 0; e < 4; ++e) {
          s += v0[e] * v0[e] + v1[e] * v1[e];
          w[e]     = f32_to_bf16_rne(v0[e]);
          w[e + 4] = f32_to_bf16_rne(v1[e]);
        }
        ssy[it] += s;
        const int idx = (row * KH + c0) ^ ((row & 7) << 3);
        *(u16x8*)&Ys[idx] = w;
      }
    }

    if (half == 1) {
      #pragma unroll
      for (int it = 0; it < 4; ++it) {
        float sx = ssx[it], sy = ssy[it];
        sx += __shfl_xor(sx, 1); sy += __shfl_xor(sy, 1);
        sx += __shfl_xor(sx, 2); sy += __shfl_xor(sy, 2);
        sx += __shfl_xor(sx, 4); sy += __shfl_xor(sy, 4);
        if ((tid & 7) == 0) {
          xsq[it * 32 + rsub] = sx;
          ysq[it * 32 + rsub] = sy;
        }
      }
    }
    __syncthreads();

    // ---- MFMA over this K-half, SWAPPED operands: D[m-frag][n-frag] --------
    // acc[i][j] value at (lane fr,kg; reg r): n = wr+i*16+fr, m = wc+j*16+kg*4+r
    #pragma unroll
    for (int kk = 0; kk < 2; ++kk) {
      bf16x8 a[4], bfj[4];
      #pragma unroll
      for (int i = 0; i < 4; ++i) {
        const int row = wr + i * 16 + fr;
        const int idx = (row * KH + kk * 32 + kg * 8) ^ ((row & 7) << 3);
        a[i] = __builtin_bit_cast(bf16x8, *(const u16x8*)&Xs[idx]);
      }
      #pragma unroll
      for (int j = 0; j < 4; ++j) {
        const int row = wc + j * 16 + fr;
        const int idx = (row * KH + kk * 32 + kg * 8) ^ ((row & 7) << 3);
        bfj[j] = __builtin_bit_cast(bf16x8, *(const u16x8*)&Ys[idx]);
      }
      #pragma unroll
      for (int i = 0; i < 4; ++i)
        #pragma unroll
        for (int j = 0; j < 4; ++j)
          acc[i][j] = __builtin_amdgcn_mfma_f32_16x16x32_bf16(bfj[j], a[i], acc[i][j], 0, 0, 0);
    }
  }

  // ---- epilogue: d2 -> 1/(1+sqrt) -> LDS transpose -> full-line nt stores --
  const float xv0 = xsq[wr + fr];         // per-i: xsq[wr + i*16 + fr]
  const float xv1 = xsq[wr + 16 + fr];
  const float xv2 = xsq[wr + 32 + fr];
  const float xv3 = xsq[wr + 48 + fr];
  const float xv[4] = {xv0, xv1, xv2, xv3};
  f32x4 yv4[4];
  #pragma unroll
  for (int j = 0; j < 4; ++j)
    yv4[j] = *(const f32x4*)&ysq[wc + j * 16 + kg * 4];

  __syncthreads();  // all waves done reading Xs/Ys for MFMA

  float* tr = (float*)smem + wid * 2048;  // wave-private 8 KB
  const int l8 = lane & 7;
  const int k8 = lane >> 3;
  float* outb = out + (size_t)b * Nn * Mm
              + (size_t)(bn * TILE + wr) * Mm + bm * TILE + wc;

  #pragma unroll
  for (int jh = 0; jh < 2; ++jh) {
    // write phase: 8 x ds_write_b128, XOR-swizzled words
    #pragma unroll
    for (int i = 0; i < 4; ++i) {
      #pragma unroll
      for (int jj = 0; jj < 2; ++jj) {
        const int j = jh * 2 + jj;
        f32x4 ov;
        #pragma unroll
        for (int r = 0; r < 4; ++r) {
          float d2 = fmaf(-2.0f, acc[i][j][r], xv[i] + yv4[j][r]);
          d2 = fmaxf(d2, 1e-7f);
          ov[r] = __builtin_amdgcn_rcpf(1.0f + __builtin_amdgcn_sqrtf(d2));
        }
        const int w = (i * 16 + fr) * 32 + ((jj * 16 + kg * 4) ^ ((fr & 7) << 2));
        *(f32x4*)&tr[w] = ov;
      }
    }
    // read phase: 8 rows x 32 contiguous floats per instruction = full lines
    #pragma unroll
    for (int it = 0; it < 8; ++it) {
      const int rr = it * 8 + k8;
      const int w  = rr * 32 + ((l8 * 4) ^ ((k8 & 7) << 2));
      f32x4 v = *(const f32x4*)&tr[w];
      float* dst = outb + (size_t)rr * Mm + jh * 32 + l8 * 4;
      __builtin_nontemporal_store(v, (f32x4*)dst);
    }
  }
}

extern "C" void kernel_launch(void* const* d_in, const int* in_sizes, int n_in,
                              void* d_out, int out_size, void* d_ws, size_t ws_size,
                              hipStream_t stream) {
  const float* X = (const float*)d_in[0];
  const float* Y = (const float*)d_in[1];
  float* out = (float*)d_out;
  dist_sim_kernel<<<dim3(NWG), dim3(256, 1, 1), 0, stream>>>(X, Y, out);
}

// Round 5
// 127.642 us; speedup vs baseline: 2.5135x; 1.5634x over previous
//
#include <hip/hip_runtime.h>
#include <hip/hip_bf16.h>

// X: [16, 2048, 128] f32, Y: [16, 2048, 128] f32 -> out: [16, 2048, 2048] f32
// out[b,n,m] = 1/(1+sqrt(max(||x||^2+||y||^2-2 x.y, 1e-7)))
#define Bb   16
#define Nn   2048
#define Mm   2048
#define Dd   128
#define TILE 128
#define KH   64                                  // K half staged per pass
#define NWG  (Bb * (Nn / TILE) * (Mm / TILE))    // 4096

typedef __attribute__((ext_vector_type(4))) float          f32x4;
typedef __attribute__((ext_vector_type(8))) unsigned short u16x8;
typedef __attribute__((ext_vector_type(8))) __bf16         bf16x8;

__device__ __forceinline__ unsigned short f32_to_bf16_rne(float f) {
  unsigned int u = __builtin_bit_cast(unsigned int, f);
  u += 0x7fffu + ((u >> 16) & 1u);
  return (unsigned short)(u >> 16);
}

// One block (512 thr, 8 waves) = one 128x128 tile; each wave a 64x32 quadrant.
// LDS deliberately padded to ~55 KB so at most 2 blocks/CU are resident:
// live output footprint = 2 x 64KB x 32 CU = 4 MB/XCD = L2 size. R0 vs R1-R3
// counters show this is the regime where L2 merges stores (WRITE = 1.04x
// ideal) instead of thrashing (3x + RFO). Occupancy stays 16 waves/CU.
__global__ __launch_bounds__(512, 4)
void dist_sim_kernel(const float* __restrict__ X, const float* __restrict__ Y,
                     float* __restrict__ out) {
  // 27648 shorts = 54 KB declared (16384 used); + 1 KB norms -> 55.3 KB/block.
  __shared__ alignas(16) unsigned short smem[27648];
  __shared__ float xsq[TILE];
  __shared__ float ysq[TILE];
  unsigned short* Xs = smem;                 // [TILE][KH] bf16, swizzled
  unsigned short* Ys = smem + TILE * KH;     // [TILE][KH] bf16, swizzled

  const int tid = threadIdx.x;

  // Bijective XCD-chunked swizzle (NWG % 8 == 0).
  const int wg  = blockIdx.x;
  const int swz = (wg & 7) * (NWG / 8) + (wg >> 3);
  const int bm  = swz & 15;
  const int bn  = (swz >> 4) & 15;
  const int b   = swz >> 8;

  const float* Xb = X + ((size_t)b * Nn + (size_t)bn * TILE) * Dd;
  const float* Yb = Y + ((size_t)b * Mm + (size_t)bm * TILE) * Dd;

  // Staging map: 512 threads, thread t -> row it*64 + (t>>3), 8 floats at (t&7)*8.
  const int rsub = tid >> 3;        // 0..63
  const int c0   = (tid & 7) * 8;   // 0..56

  float ssx[2] = {0.f, 0.f};
  float ssy[2] = {0.f, 0.f};

  const int lane = tid & 63;
  const int wid  = tid >> 6;           // 0..7
  const int wr   = (wid >> 2) * 64;    // 0 or 64
  const int wc   = (wid & 3) * 32;     // 0,32,64,96
  const int fr   = lane & 15;
  const int kg   = lane >> 4;          // 0..3

  f32x4 acc[4][2];
  #pragma unroll
  for (int i = 0; i < 4; ++i)
    #pragma unroll
    for (int j = 0; j < 2; ++j)
      acc[i][j] = (f32x4){0.f, 0.f, 0.f, 0.f};

  #pragma unroll
  for (int half = 0; half < 2; ++half) {
    if (half == 1) __syncthreads();  // protect re-stage from half-0 readers

    // ---- stage: global f32 -> LDS bf16 (swizzled), accumulate f32 norms ----
    #pragma unroll
    for (int it = 0; it < 2; ++it) {
      const int row = it * 64 + rsub;
      {
        const float* p = Xb + row * Dd + half * KH + c0;
        f32x4 v0 = *(const f32x4*)(p);
        f32x4 v1 = *(const f32x4*)(p + 4);
        u16x8 w;
        float s = 0.f;
        #pragma unroll
        for (int e = 0; e < 4; ++e) {
          s += v0[e] * v0[e] + v1[e] * v1[e];
          w[e]     = f32_to_bf16_rne(v0[e]);
          w[e + 4] = f32_to_bf16_rne(v1[e]);
        }
        ssx[it] += s;
        const int idx = (row * KH + c0) ^ ((row & 7) << 3);  // bank swizzle
        *(u16x8*)&Xs[idx] = w;
      }
      {
        const float* p = Yb + row * Dd + half * KH + c0;
        f32x4 v0 = *(const f32x4*)(p);
        f32x4 v1 = *(const f32x4*)(p + 4);
        u16x8 w;
        float s = 0.f;
        #pragma unroll
        for (int e = 0; e < 4; ++e) {
          s += v0[e] * v0[e] + v1[e] * v1[e];
          w[e]     = f32_to_bf16_rne(v0[e]);
          w[e + 4] = f32_to_bf16_rne(v1[e]);
        }
        ssy[it] += s;
        const int idx = (row * KH + c0) ^ ((row & 7) << 3);
        *(u16x8*)&Ys[idx] = w;
      }
    }

    // Publish f32 row norms after the last stage pass (8 lanes per row,
    // lanes sharing a row are consecutive within a wave).
    if (half == 1) {
      #pragma unroll
      for (int it = 0; it < 2; ++it) {
        float sx = ssx[it], sy = ssy[it];
        sx += __shfl_xor(sx, 1); sy += __shfl_xor(sy, 1);
        sx += __shfl_xor(sx, 2); sy += __shfl_xor(sy, 2);
        sx += __shfl_xor(sx, 4); sy += __shfl_xor(sy, 4);
        if ((tid & 7) == 0) {
          xsq[it * 64 + rsub] = sx;
          ysq[it * 64 + rsub] = sy;
        }
      }
    }
    __syncthreads();

    // ---- MFMA over this K-half, swapped operands: D[m-frag][n-frag] --------
    // acc[i][j] value (lane fr,kg; reg r): n = wr+i*16+fr, m = wc+j*16+kg*4+r
    #pragma unroll
    for (int kk = 0; kk < 2; ++kk) {
      bf16x8 a[4], bb[2];
      #pragma unroll
      for (int i = 0; i < 4; ++i) {
        const int row = wr + i * 16 + fr;
        const int idx = (row * KH + kk * 32 + kg * 8) ^ ((row & 7) << 3);
        a[i] = __builtin_bit_cast(bf16x8, *(const u16x8*)&Xs[idx]);
      }
      #pragma unroll
      for (int j = 0; j < 2; ++j) {
        const int row = wc + j * 16 + fr;
        const int idx = (row * KH + kk * 32 + kg * 8) ^ ((row & 7) << 3);
        bb[j] = __builtin_bit_cast(bf16x8, *(const u16x8*)&Ys[idx]);
      }
      #pragma unroll
      for (int i = 0; i < 4; ++i)
        #pragma unroll
        for (int j = 0; j < 2; ++j)
          acc[i][j] = __builtin_amdgcn_mfma_f32_16x16x32_bf16(bb[j], a[i], acc[i][j], 0, 0, 0);
    }
  }

  // ---- epilogue: d2 -> 1/(1+sqrt(d2)), direct f32x4 stores -----------------
  float xv[4];
  #pragma unroll
  for (int i = 0; i < 4; ++i) xv[i] = xsq[wr + i * 16 + fr];
  f32x4 yv[2];
  #pragma unroll
  for (int j = 0; j < 2; ++j) yv[j] = *(const f32x4*)&ysq[wc + j * 16 + kg * 4];

  float* outb = out + (size_t)b * Nn * Mm
              + (size_t)(bn * TILE) * Mm + bm * TILE;
  #pragma unroll
  for (int i = 0; i < 4; ++i) {
    const int n = wr + i * 16 + fr;
    float* orow = outb + (size_t)n * Mm;
    #pragma unroll
    for (int j = 0; j < 2; ++j) {
      f32x4 ov;
      #pragma unroll
      for (int r = 0; r < 4; ++r) {
        float d2 = fmaf(-2.0f, acc[i][j][r], xv[i] + yv[j][r]);
        d2 = fmaxf(d2, 1e-7f);
        ov[r] = __builtin_amdgcn_rcpf(1.0f + __builtin_amdgcn_sqrtf(d2));
      }
      *(f32x4*)&orow[wc + j * 16 + kg * 4] = ov;
    }
  }
}

extern "C" void kernel_launch(void* const* d_in, const int* in_sizes, int n_in,
                              void* d_out, int out_size, void* d_ws, size_t ws_size,
                              hipStream_t stream) {
  const float* X = (const float*)d_in[0];
  const float* Y = (const float*)d_in[1];
  float* out = (float*)d_out;
  dist_sim_kernel<<<dim3(NWG), dim3(512, 1, 1), 0, stream>>>(X, Y, out);
}